// Round 8
// baseline (830.488 us; speedup 1.0000x reference)
//
#include <hip/hip_runtime.h>

#define N_NODES 20000
#define N_EDGES 320000
#define SEQ 8

typedef __attribute__((ext_vector_type(8))) short bf16x8;
typedef __attribute__((ext_vector_type(4))) float floatx4;
typedef const unsigned int __attribute__((address_space(1)))* gas_u32;
typedef unsigned int __attribute__((address_space(3)))* las_u32;

__device__ __forceinline__ unsigned short f2bf(float f) {
  unsigned int u = __builtin_bit_cast(unsigned int, f);
  return (unsigned short)((u + 0x7fffu + ((u >> 16) & 1u)) >> 16);
}
__device__ __forceinline__ float bflo(unsigned int u) {
  return __builtin_bit_cast(float, u << 16);
}
__device__ __forceinline__ float bfhi(unsigned int u) {
  return __builtin_bit_cast(float, u & 0xffff0000u);
}
__device__ __forceinline__ float sigf(float x) { return 1.f / (1.f + __expf(-x)); }

// async global->LDS, 16B per lane; LDS dest = wave-uniform base + lane*16
__device__ __forceinline__ void gl_lds16(const void* g, void* l) {
  auto gp = (gas_u32)g;
  auto lp = (las_u32)(unsigned int)(unsigned long long)l;  // strip aperture
  __builtin_amdgcn_global_load_lds(gp, lp, 16, 0, 0);
}

// ---------------- setup kernels ----------------

__global__ void k_prologue(const float* __restrict__ Wi,
                           const float* __restrict__ Wc,
                           const float* __restrict__ bc,
                           unsigned short* __restrict__ WiT,
                           unsigned short* __restrict__ W1T,
                           unsigned short* __restrict__ W2T,
                           float* __restrict__ bcp,
                           float* __restrict__ deg, int* __restrict__ counts) {
  int idx = blockIdx.x * 256 + threadIdx.x;  // 0..131071
  if (idx < N_NODES) { deg[idx] = 1.0f; counts[idx] = 0; }
  if (idx < 65536) {
    int n = idx >> 8, k = idx & 255;
    WiT[n * 256 + k] = f2bf(Wi[k * 256 + n]);
  }
  if (idx < 512) bcp[idx] = bc[((idx & 3) << 7) | (idx >> 2)];
  int n2 = idx >> 8, k2 = idx & 255;  // n2 0..511
  if (k2 < 128) {
    int orig = ((n2 & 3) << 7) | (n2 >> 2);
    W1T[n2 * 128 + k2] = f2bf(Wc[k2 * 512 + orig]);
    W2T[n2 * 128 + k2] = f2bf(Wc[(k2 + 128) * 512 + orig]);
  }
}

__global__ void k_deg(const int* __restrict__ ei, const float* __restrict__ ea,
                      float* __restrict__ deg, int* __restrict__ counts) {
  int e = blockIdx.x * 256 + threadIdx.x;
  if (e >= N_EDGES) return;
  int d = ei[N_EDGES + e];
  atomicAdd(&deg[d], ea[e]);
  atomicAdd(&counts[d], 1);
}

// single-block scan: counts -> exclusive row_ptr/cursor; dinv = rsqrt(deg)
__global__ __launch_bounds__(1024) void k_scan(
    const int* __restrict__ counts, const float* __restrict__ deg,
    float* __restrict__ dinv, int* __restrict__ row_ptr,
    int* __restrict__ cursor) {
  __shared__ int sm[1024];
  int t = threadIdx.x;
  int base = t * 20;
  int local[20];
  int s = 0;
#pragma unroll
  for (int i = 0; i < 20; ++i) {
    int g = base + i;
    int v = (g < N_NODES) ? counts[g] : 0;
    local[i] = v;
    s += v;
  }
  sm[t] = s;
  __syncthreads();
  for (int o = 1; o < 1024; o <<= 1) {
    int add = (t >= o) ? sm[t - o] : 0;
    __syncthreads();
    sm[t] += add;
    __syncthreads();
  }
  int run = sm[t] - s;
#pragma unroll
  for (int i = 0; i < 20; ++i) {
    int g = base + i;
    if (g < N_NODES) {
      row_ptr[g] = run;
      cursor[g] = run;
      dinv[g] = rsqrtf(deg[g]);
    }
    run += local[i];
  }
  if (t == 0) row_ptr[N_NODES] = N_EDGES;
}

__global__ void k_fill(const int* __restrict__ ei, const float* __restrict__ ea,
                       const float* __restrict__ dinv, int* __restrict__ cursor,
                       int* __restrict__ csr_src, float* __restrict__ csr_w) {
  int e = blockIdx.x * 256 + threadIdx.x;
  if (e >= N_EDGES) return;
  int s = ei[e], d = ei[N_EDGES + e];
  int k = atomicAdd(&cursor[d], 1);
  csr_src[k] = s;
  csr_w[k] = dinv[s] * ea[e] * dinv[d];
}

// ---------------- init aggregation (one wave per node, shfl-broadcast) -------

__global__ __launch_bounds__(256) void k_agg_init(
    const float* __restrict__ h, const float* __restrict__ c,
    unsigned int* __restrict__ AhAc_u, const float* __restrict__ dinv,
    const int* __restrict__ row_ptr, const int* __restrict__ csr_src,
    const float* __restrict__ csr_w) {
  int wid = (blockIdx.x * 256 + threadIdx.x) >> 6;
  int lane = threadIdx.x & 63;
  if (wid >= N_NODES) return;
  float di = dinv[wid], dd = di * di;
  const float4* xb = (lane < 32) ? (const float4*)h : (const float4*)c;
  int lcol = lane & 31;
  float4 a = xb[(size_t)wid * 32 + lcol];
  float s0 = a.x * dd, s1 = a.y * dd, s2 = a.z * dd, s3 = a.w * dd;
  int e0 = row_ptr[wid], end = row_ptr[wid + 1];
  for (int base = e0; base < end; base += 64) {
    int n = end - base;
    if (n > 64) n = 64;
    int sl = 0;
    float wl = 0.f;
    if (base + lane < end) {
      sl = csr_src[base + lane];
      wl = csr_w[base + lane];
    }
    int j = 0;
    for (; j + 4 <= n; j += 4) {
      int sa = __shfl(sl, j), sb = __shfl(sl, j + 1);
      int sc = __shfl(sl, j + 2), sd = __shfl(sl, j + 3);
      float wa = __shfl(wl, j), wb = __shfl(wl, j + 1);
      float wc = __shfl(wl, j + 2), wd = __shfl(wl, j + 3);
      float4 va = xb[(size_t)sa * 32 + lcol];
      float4 vb = xb[(size_t)sb * 32 + lcol];
      float4 vc = xb[(size_t)sc * 32 + lcol];
      float4 vd = xb[(size_t)sd * 32 + lcol];
      s0 += va.x * wa; s1 += va.y * wa; s2 += va.z * wa; s3 += va.w * wa;
      s0 += vb.x * wb; s1 += vb.y * wb; s2 += vb.z * wb; s3 += vb.w * wb;
      s0 += vc.x * wc; s1 += vc.y * wc; s2 += vc.z * wc; s3 += vc.w * wc;
      s0 += vd.x * wd; s1 += vd.y * wd; s2 += vd.z * wd; s3 += vd.w * wd;
    }
    for (; j < n; ++j) {
      int sa = __shfl(sl, j);
      float wa = __shfl(wl, j);
      float4 va = xb[(size_t)sa * 32 + lcol];
      s0 += va.x * wa; s1 += va.y * wa; s2 += va.z * wa; s3 += va.w * wa;
    }
  }
  uint2 o;
  o.x = (unsigned int)f2bf(s0) | ((unsigned int)f2bf(s1) << 16);
  o.y = (unsigned int)f2bf(s2) | ((unsigned int)f2bf(s3) << 16);
  ((uint2*)AhAc_u)[(size_t)wid * 64 + lane] = o;
}

// ---------------- init GEMMs (unchanged structure from R7) -------------------
// EPI 0 (init, KK=256): v += bias[gcol]; elu; col<128 -> hbf else c_cur.
// EPI 1 (Kbuf build, KK=128): Kbuf = v + bcp[gcol]  (gate-interleaved cols).
template <int EPI, int KK, int LDA>
__global__ __launch_bounds__(256) void k_gemm(
    const unsigned short* __restrict__ A, const unsigned short* __restrict__ BT,
    const float* __restrict__ bias, float* __restrict__ c_cur,
    unsigned short* __restrict__ hbf, float* __restrict__ out0) {
  __shared__ __align__(16) struct {
    unsigned short a[128 * 64];
    unsigned short b[128 * 64];
  } sm;
  const int M = N_NODES;
  int tid = threadIdx.x;
  int bm0 = blockIdx.x * 128, bn0 = blockIdx.y * 128;
  int wave = tid >> 6, lane = tid & 63;
  int wrow = (wave >> 1) * 64, wcol = (wave & 1) * 64;
  int lr = lane & 15, lq = lane >> 4;
  int key = lr & 7;
  int lr8 = lane >> 3, cq = lane & 7;
  int gq8 = (cq ^ lr8) * 8;

  floatx4 acc[4][4];
#pragma unroll
  for (int i = 0; i < 4; i++)
#pragma unroll
    for (int j = 0; j < 4; j++) acc[i][j] = (floatx4){0.f, 0.f, 0.f, 0.f};

  for (int k0 = 0; k0 < KK; k0 += 64) {
    __syncthreads();
#pragma unroll
    for (int p = 0; p < 4; ++p) {
      int row = p * 32 + wave * 8;
      int ra = bm0 + row + lr8;
      if (ra > M - 1) ra = M - 1;
      gl_lds16(A + (size_t)ra * LDA + k0 + gq8, sm.a + row * 64);
      gl_lds16(BT + (size_t)(bn0 + row + lr8) * KK + k0 + gq8,
               sm.b + row * 64);
    }
    __syncthreads();
#pragma unroll
    for (int ks = 0; ks < 2; ++ks) {
      int q = ks * 4 + lq;
      int slot = (q ^ key) << 3;
      bf16x8 af[4], bfr[4];
#pragma unroll
      for (int mi = 0; mi < 4; mi++)
        af[mi] = *(const bf16x8*)(sm.a + (wrow + mi * 16 + lr) * 64 + slot);
#pragma unroll
      for (int ni = 0; ni < 4; ni++)
        bfr[ni] = *(const bf16x8*)(sm.b + (wcol + ni * 16 + lr) * 64 + slot);
#pragma unroll
      for (int mi = 0; mi < 4; mi++)
#pragma unroll
        for (int ni = 0; ni < 4; ni++)
          acc[mi][ni] = __builtin_amdgcn_mfma_f32_16x16x32_bf16(
              af[mi], bfr[ni], acc[mi][ni], 0, 0, 0);
    }
  }

#pragma unroll
  for (int mi = 0; mi < 4; mi++) {
#pragma unroll
    for (int r = 0; r < 4; r++) {
      int grow = bm0 + wrow + mi * 16 + lq * 4 + r;
      if (grow >= M) continue;
#pragma unroll
      for (int ni = 0; ni < 4; ni++) {
        int gcol = bn0 + wcol + ni * 16 + lr;
        if (EPI == 0) {
          float v = acc[mi][ni][r] + bias[gcol];
          v = (v > 0.f) ? v : expm1f(v);
          if (gcol < 128) hbf[(size_t)grow * 128 + gcol] = f2bf(v);
          else c_cur[(size_t)grow * 128 + gcol - 128] = v;
        } else {
          out0[(size_t)grow * 512 + gcol] = acc[mi][ni][r] + bias[gcol];
        }
      }
    }
  }
}

// ---------------- fused step kernel: agg + GEMM + gates, one launch ----------
// Block owns M-rows [bm0, bm0+64). Phase 1: shfl-gather-aggregate own rows
// from hbf_prev into padded LDS A-tile (bf16). Phase 2: 4 N-passes of
// C[64x128] = A[64x128] @ W2T-tile^T with fused LSTM gates (Kbuf carries
// the step-invariant Ah@W1 + b_cell part). Writes hbf_next (double buffer).
__global__ __launch_bounds__(256, 2) void k_step(
    const unsigned int* __restrict__ hbf_prev,
    unsigned short* __restrict__ hbf_next,
    const unsigned short* __restrict__ W2T, const float* __restrict__ Kbuf,
    float* __restrict__ c_cur, const float* __restrict__ dinv,
    const int* __restrict__ row_ptr, const int* __restrict__ csr_src,
    const float* __restrict__ csr_w, float* __restrict__ out_t) {
  __shared__ __align__(16) unsigned short sA[64 * 136];  // +8 pad: bank-safe
  __shared__ __align__(16) union {
    unsigned short b[2][128 * 64];  // both k0-chunks of one N-pass (32 KB)
    float ep[64 * 132];             // epilogue transpose buffer (33.8 KB)
  } sB;
  int tid = threadIdx.x;
  int wave = tid >> 6, lane = tid & 63;
  int bm0 = blockIdx.x * 64;

  // ---- Phase 1: aggregate own 64 rows into sA ----
  for (int i = 0; i < 16; ++i) {
    int rloc = wave * 16 + i;
    int wid = bm0 + rloc;
    unsigned int packed = 0u;
    if (wid < N_NODES) {
      float di = dinv[wid], dd = di * di;
      unsigned int a = hbf_prev[(size_t)wid * 64 + lane];
      float s0 = bflo(a) * dd, s1 = bfhi(a) * dd;
      int e0 = row_ptr[wid], end = row_ptr[wid + 1];
      for (int base = e0; base < end; base += 64) {
        int n = end - base;
        if (n > 64) n = 64;
        int sl = 0;
        float wl = 0.f;
        if (base + lane < end) {
          sl = csr_src[base + lane];
          wl = csr_w[base + lane];
        }
        int j = 0;
        for (; j + 4 <= n; j += 4) {
          int sa = __shfl(sl, j), sb = __shfl(sl, j + 1);
          int sc = __shfl(sl, j + 2), sd = __shfl(sl, j + 3);
          float wa = __shfl(wl, j), wb = __shfl(wl, j + 1);
          float wc = __shfl(wl, j + 2), wd = __shfl(wl, j + 3);
          unsigned int va = hbf_prev[(size_t)sa * 64 + lane];
          unsigned int vb = hbf_prev[(size_t)sb * 64 + lane];
          unsigned int vc = hbf_prev[(size_t)sc * 64 + lane];
          unsigned int vd = hbf_prev[(size_t)sd * 64 + lane];
          s0 += bflo(va) * wa; s1 += bfhi(va) * wa;
          s0 += bflo(vb) * wb; s1 += bfhi(vb) * wb;
          s0 += bflo(vc) * wc; s1 += bfhi(vc) * wc;
          s0 += bflo(vd) * wd; s1 += bfhi(vd) * wd;
        }
        for (; j < n; ++j) {
          int sa = __shfl(sl, j);
          float wa = __shfl(wl, j);
          unsigned int va = hbf_prev[(size_t)sa * 64 + lane];
          s0 += bflo(va) * wa; s1 += bfhi(va) * wa;
        }
      }
      packed = (unsigned int)f2bf(s0) | ((unsigned int)f2bf(s1) << 16);
    }
    *(unsigned int*)(sA + rloc * 136 + lane * 2) = packed;
  }

  // ---- Phase 2: 4 N-passes of GEMM + gates ----
  int lr = lane & 15, lq = lane >> 4;
  int key = lr & 7;
  int lr8 = lane >> 3, cq = lane & 7;
  int gq8 = (cq ^ lr8) * 8;

  for (int npass = 0; npass < 4; ++npass) {
    int bn0 = npass * 128;
    __syncthreads();  // sA ready (first pass) / ep dead (later passes)
    // stage both k0 chunks of B = W2T rows [bn0, bn0+128)
#pragma unroll
    for (int half = 0; half < 2; ++half) {
#pragma unroll
      for (int p = 0; p < 4; ++p) {
        int row = p * 32 + wave * 8;
        gl_lds16(W2T + (size_t)(bn0 + row + lr8) * 128 + half * 64 + gq8,
                 sB.b[half] + row * 64);
      }
    }
    __syncthreads();

    floatx4 acc[4][2];
#pragma unroll
    for (int i = 0; i < 4; i++) {
      acc[i][0] = (floatx4){0.f, 0.f, 0.f, 0.f};
      acc[i][1] = (floatx4){0.f, 0.f, 0.f, 0.f};
    }
#pragma unroll
    for (int half = 0; half < 2; ++half) {
#pragma unroll
      for (int ks = 0; ks < 2; ++ks) {
        int q = ks * 4 + lq;
        int slot = (q ^ key) << 3;
        int kofs = half * 64 + ks * 32 + lq * 8;
        bf16x8 af[4], bfr[2];
#pragma unroll
        for (int mi = 0; mi < 4; mi++)
          af[mi] = *(const bf16x8*)(sA + (mi * 16 + lr) * 136 + kofs);
#pragma unroll
        for (int ni = 0; ni < 2; ni++)
          bfr[ni] = *(const bf16x8*)(sB.b[half] +
                                     (wave * 32 + ni * 16 + lr) * 64 + slot);
#pragma unroll
        for (int mi = 0; mi < 4; mi++)
#pragma unroll
          for (int ni = 0; ni < 2; ni++)
            acc[mi][ni] = __builtin_amdgcn_mfma_f32_16x16x32_bf16(
                af[mi], bfr[ni], acc[mi][ni], 0, 0, 0);
      }
    }
    __syncthreads();  // B dead; reuse as ep

    // transpose C into ep: row = mi*16 + lq*4 + r, col = wave*32 + ni*16 + lr
#pragma unroll
    for (int mi = 0; mi < 4; mi++)
#pragma unroll
      for (int r = 0; r < 4; r++) {
        int row_l = mi * 16 + lq * 4 + r;
#pragma unroll
        for (int ni = 0; ni < 2; ni++)
          sB.ep[row_l * 132 + wave * 32 + ni * 16 + lr] = acc[mi][ni][r];
      }
    __syncthreads();

    // gates: 64 rows x 32 outputs for this npass
#pragma unroll
    for (int it = 0; it < 8; ++it) {
      int p = tid + it * 256;
      int row_l = p >> 5, j = p & 31;
      int grow = bm0 + row_l;
      if (grow < N_NODES) {
        int jg = npass * 32 + j;
        const float* eb = sB.ep + row_l * 132 + 4 * j;
        float4 kb = *(const float4*)&Kbuf[(size_t)grow * 512 + bn0 + 4 * j];
        float gi = eb[0] + kb.x;
        float gf = eb[1] + kb.y;
        float go = eb[2] + kb.z;
        float gg = eb[3] + kb.w;
        size_t o = (size_t)grow * 128 + jg;
        float cp = c_cur[o];
        float cn = sigf(gf) * cp + sigf(gi) * tanhf(gg);
        float hn = sigf(go) * tanhf(cn);
        c_cur[o] = cn;
        hbf_next[o] = f2bf(hn);
        out_t[o] = hn;
      }
    }
  }
}

// ---------------- host launcher ----------------
extern "C" void kernel_launch(void* const* d_in, const int* in_sizes, int n_in,
                              void* d_out, int out_size, void* d_ws, size_t ws_size,
                              hipStream_t stream) {
  const float* h  = (const float*)d_in[0];
  const float* c  = (const float*)d_in[1];
  const int*   ei = (const int*)d_in[2];
  const float* ea = (const float*)d_in[3];
  const float* Wi = (const float*)d_in[4];
  const float* bi = (const float*)d_in[5];
  const float* Wc = (const float*)d_in[6];
  const float* bc = (const float*)d_in[7];
  float* out = (float*)d_out;

  char* w = (char*)d_ws;
  size_t off = 0;
  auto alloc = [&](size_t bytes) {
    void* p = w + off;
    off += (bytes + 511) & ~(size_t)511;
    return p;
  };
  float* deg           = (float*)alloc(N_NODES * 4);
  float* dinv          = (float*)alloc(N_NODES * 4);
  int* counts          = (int*)alloc(N_NODES * 4);
  int* cursor          = (int*)alloc(N_NODES * 4);
  int* row_ptr         = (int*)alloc((N_NODES + 1) * 4);
  int* csr_src         = (int*)alloc(N_EDGES * 4);
  float* csr_w         = (float*)alloc(N_EDGES * 4);
  unsigned short* WiT  = (unsigned short*)alloc(256 * 256 * 2);
  unsigned short* W1T  = (unsigned short*)alloc(512 * 128 * 2);
  unsigned short* W2T  = (unsigned short*)alloc(512 * 128 * 2);
  float* bcp           = (float*)alloc(512 * 4);
  unsigned short* AhAc = (unsigned short*)alloc((size_t)N_NODES * 256 * 2);
  unsigned short* hbf0 = (unsigned short*)alloc((size_t)N_NODES * 128 * 2);
  unsigned short* hbf1 = (unsigned short*)alloc((size_t)N_NODES * 128 * 2);
  float* c_cur         = (float*)alloc((size_t)N_NODES * 128 * 4);
  float* Kbuf          = (float*)alloc((size_t)N_NODES * 512 * 4);

  const int NB_E = (N_EDGES + 255) / 256;  // 1250
  const int NB_AGG = N_NODES * 64 / 256;   // 5000
  const int MB = (N_NODES + 127) / 128;    // 157
  const int SB = (N_NODES + 63) / 64;      // 313

  k_prologue<<<512, 256, 0, stream>>>(Wi, Wc, bc, WiT, W1T, W2T, bcp, deg,
                                      counts);
  k_deg<<<NB_E, 256, 0, stream>>>(ei, ea, deg, counts);
  k_scan<<<1, 1024, 0, stream>>>(counts, deg, dinv, row_ptr, cursor);
  k_fill<<<NB_E, 256, 0, stream>>>(ei, ea, dinv, cursor, csr_src, csr_w);

  k_agg_init<<<NB_AGG, 256, 0, stream>>>(h, c, (unsigned int*)AhAc, dinv,
                                         row_ptr, csr_src, csr_w);
  // states = elu([Ah|Ac]@Wi + bi) -> hbf0, c_cur
  k_gemm<0, 256, 256><<<dim3(MB, 2), 256, 0, stream>>>(AhAc, WiT, bi, c_cur,
                                                       hbf0, nullptr);
  // Kbuf = Ah@W1 + bcp (gate-interleaved), A = AhAc cols 0..127
  k_gemm<1, 128, 256><<<dim3(MB, 4), 256, 0, stream>>>(AhAc, W1T, bcp, nullptr,
                                                       nullptr, Kbuf);

  unsigned short* hb[2] = {hbf0, hbf1};
  for (int t = 0; t < SEQ; ++t) {
    k_step<<<SB, 256, 0, stream>>>((const unsigned int*)hb[t & 1],
                                   hb[(t + 1) & 1], W2T, Kbuf, c_cur, dinv,
                                   row_ptr, csr_src, csr_w,
                                   out + (size_t)t * N_NODES * 128);
  }
}